// Round 3
// baseline (8173.194 us; speedup 1.0000x reference)
//
#include <hip/hip_runtime.h>
#include <math.h>

#define B 8
#define P 2048
#define D 64
#define EPS 0.1f
#define INVEPS 10.0f
#define MAXIT 100
#define THRESH 0.1f
#define RSLAB 32
#define SLABS (P / RSLAB)          // 64 slabs per batch
#define NBLK_A (B * SLABS)         // 512 blocks for iter_rowcol

// ---------------- C build: C[b,i,j] = sum_d (x[b,i,d]-y[b,j,d])^2 ----------
__global__ __launch_bounds__(256) void build_C(const float* __restrict__ x,
                                               const float* __restrict__ y,
                                               float* __restrict__ C) {
    __shared__ float xs[64 * 68];
    __shared__ float ys[64 * 68];
    const int tid = threadIdx.x;
    const int blk = blockIdx.x;        // 8 * 32 * 32 = 8192 blocks
    const int b   = blk >> 10;
    const int rem = blk & 1023;
    const int i0  = (rem >> 5) << 6;
    const int j0  = (rem & 31) << 6;

    const float4* xg = (const float4*)(x + ((size_t)(b * P + i0)) * D);
    const float4* yg = (const float4*)(y + ((size_t)(b * P + j0)) * D);
#pragma unroll
    for (int p = 0; p < 4; ++p) {
        int q = tid + (p << 8);
        int row = q >> 4, c4 = q & 15;
        float4 xv = xg[row * 16 + c4];
        float4 yv = yg[row * 16 + c4];
        float* xd = &xs[row * 68 + (c4 << 2)];
        xd[0] = xv.x; xd[1] = xv.y; xd[2] = xv.z; xd[3] = xv.w;
        float* yd = &ys[row * 68 + (c4 << 2)];
        yd[0] = yv.x; yd[1] = yv.y; yd[2] = yv.z; yd[3] = yv.w;
    }
    __syncthreads();

    const int ti = tid >> 4, tj = tid & 15;
    float acc[4][4] = {};
#pragma unroll 4
    for (int d4 = 0; d4 < 16; ++d4) {
        float4 xa[4], yb[4];
#pragma unroll
        for (int a = 0; a < 4; ++a)
            xa[a] = *(const float4*)&xs[(ti * 4 + a) * 68 + (d4 << 2)];
#pragma unroll
        for (int bb = 0; bb < 4; ++bb)
            yb[bb] = *(const float4*)&ys[(tj * 4 + bb) * 68 + (d4 << 2)];
#pragma unroll
        for (int a = 0; a < 4; ++a)
#pragma unroll
            for (int bb = 0; bb < 4; ++bb) {
                float dx = xa[a].x - yb[bb].x;
                float dy = xa[a].y - yb[bb].y;
                float dz = xa[a].z - yb[bb].z;
                float dw = xa[a].w - yb[bb].w;
                acc[a][bb] += dx * dx + dy * dy + dz * dz + dw * dw;
            }
    }
    size_t base = ((size_t)b * P + (i0 + ti * 4)) * P + (j0 + tj * 4);
#pragma unroll
    for (int a = 0; a < 4; ++a) {
        float4 o = make_float4(acc[a][0], acc[a][1], acc[a][2], acc[a][3]);
        *(float4*)&C[base + (size_t)a * P] = o;
    }
}

// ---------------- online logsumexp helpers --------------------------------
__device__ __forceinline__ void lse_push(float z, float& m, float& s) {
    if (z > m) { s = s * __expf(m - z) + 1.0f; m = z; }
    else       { s += __expf(z - m); }
}
__device__ __forceinline__ void lse_merge(float mo, float so, float& m, float& s) {
    float M = fmaxf(m, mo);
    s = s * __expf(m - M) + so * __expf(mo - M);
    m = M;
}

// ---------------- init: zero u, v, err accumulators, done flags, cost ------
__global__ void init_ws(float* __restrict__ u, float* __restrict__ v,
                        float* __restrict__ errAcc, unsigned* __restrict__ doneArr,
                        float* __restrict__ cost) {
    int idx = blockIdx.x * blockDim.x + threadIdx.x;
    if (idx < B * P) { u[idx] = 0.0f; v[idx] = 0.0f; }
    if (idx < MAXIT) errAcc[idx] = 0.0f;
    if (idx <= MAXIT) doneArr[idx] = 0u;
    if (idx < B) cost[idx] = 0.0f;
}

// ---- iteration kernel A: row-LSE (u update + err) then column partials ----
// block = (batch, slab of RSLAB rows); 256 threads.
__global__ __launch_bounds__(256) void iter_rowcol(
        const float* __restrict__ C, const float* __restrict__ vg,
        float* __restrict__ u, float2* __restrict__ part,
        float* __restrict__ errAcc, const unsigned* __restrict__ doneArr, int t) {
    if (doneArr[t]) return;
    __shared__ float su[RSLAB];
    __shared__ float serr[4];
    const int tid = threadIdx.x, lane = tid & 63, wid = tid >> 6;
    const int b    = blockIdx.x >> 6;      // / SLABS
    const int slab = blockIdx.x & (SLABS - 1);
    const int r0   = slab * RSLAB;
    const float* Cb = C + (size_t)b * P * P;
    const float4* vrow = (const float4*)(vg + b * P);
    const float eps_logmu = EPS * logf(1.0f / (float)P + 1e-8f);

    // ---- row pass: u_new[r] = eps*log_mu - eps*LSE_j((v_j - C_rj)/eps) ----
    float werr = 0.0f;
    for (int rr = wid; rr < RSLAB; rr += 4) {
        const float4* Crow = (const float4*)(Cb + (size_t)(r0 + rr) * P);
        float m = -INFINITY, s = 0.0f;
        for (int it = lane; it < P / 4; it += 64) {
            float4 c4 = Crow[it];
            float4 v4 = vrow[it];
            lse_push((v4.x - c4.x) * INVEPS, m, s);
            lse_push((v4.y - c4.y) * INVEPS, m, s);
            lse_push((v4.z - c4.z) * INVEPS, m, s);
            lse_push((v4.w - c4.w) * INVEPS, m, s);
        }
#pragma unroll
        for (int off = 32; off; off >>= 1) {
            float mo = __shfl_xor(m, off, 64);
            float so = __shfl_xor(s, off, 64);
            lse_merge(mo, so, m, s);
        }
        float unew = eps_logmu - EPS * (m + logf(s));
        if (lane == 0) {
            int gi = b * P + r0 + rr;
            werr += fabsf(unew - u[gi]);
            u[gi] = unew;
            su[rr] = unew;
        }
    }
    if (lane == 0) serr[wid] = werr;
    __syncthreads();                 // publishes su[] and serr[]
    if (tid == 0) atomicAdd(&errAcc[t], serr[0] + serr[1] + serr[2] + serr[3]);

    // ---- column partials over this slab: cols 4*tid..+3 and +1024 ----
    float m[8], s[8];
#pragma unroll
    for (int k = 0; k < 8; ++k) { m[k] = -INFINITY; s[k] = 0.0f; }
    const int j0 = tid << 2;
    for (int rr = 0; rr < RSLAB; ++rr) {
        float ur = su[rr];
        const float* crow = Cb + (size_t)(r0 + rr) * P;
        float4 c0 = *(const float4*)(crow + j0);
        float4 c1 = *(const float4*)(crow + j0 + 1024);
        lse_push((ur - c0.x) * INVEPS, m[0], s[0]);
        lse_push((ur - c0.y) * INVEPS, m[1], s[1]);
        lse_push((ur - c0.z) * INVEPS, m[2], s[2]);
        lse_push((ur - c0.w) * INVEPS, m[3], s[3]);
        lse_push((ur - c1.x) * INVEPS, m[4], s[4]);
        lse_push((ur - c1.y) * INVEPS, m[5], s[5]);
        lse_push((ur - c1.z) * INVEPS, m[6], s[6]);
        lse_push((ur - c1.w) * INVEPS, m[7], s[7]);
    }
#pragma unroll
    for (int k = 0; k < 8; ++k) {
        int j = (k < 4) ? (j0 + k) : (j0 + 1024 + (k - 4));
        part[(size_t)slab * (B * P) + b * P + j] = make_float2(m[k], s[k]);
    }
}

// ---- iteration kernel B: merge slab partials -> v; latch done flag --------
__global__ void iter_merge(const float2* __restrict__ part, float* __restrict__ vg,
                           const float* __restrict__ errAcc,
                           unsigned* __restrict__ doneArr, int t) {
    int idx = blockIdx.x * blockDim.x + threadIdx.x;   // 0..B*P-1
    if (idx == 0) {
        // errAcc[t]==0 when frozen, so the latch self-propagates.
        doneArr[t + 1] = doneArr[t] | (errAcc[t] < THRESH * (float)B ? 1u : 0u);
    }
    if (doneArr[t]) return;
    const float eps_logmu = EPS * logf(1.0f / (float)P + 1e-8f);  // log_nu == log_mu
    float m = -INFINITY, s = 0.0f;
#pragma unroll 8
    for (int k = 0; k < SLABS; ++k) {
        float2 pk = part[(size_t)k * (B * P) + idx];
        lse_merge(pk.x, pk.y, m, s);
    }
    vg[idx] = eps_logmu - EPS * (m + logf(s));
}

// ---- final: pi = exp((u+v-C)/eps), cost[b] = sum pi*C ---------------------
// 1024 blocks * 4 waves * 4 rows = 16384 rows = B*P.
__global__ __launch_bounds__(256) void final_pi_cost(
        const float* __restrict__ C, const float* __restrict__ u,
        const float* __restrict__ vg, float* __restrict__ pi,
        float* __restrict__ cost) {
    __shared__ float sc[B];
    const int tid = threadIdx.x, lane = tid & 63, wid = tid >> 6;
    if (tid < B) sc[tid] = 0.0f;
    __syncthreads();
    const int gw = blockIdx.x * 4 + wid;      // 0..4095
    const int rbase = gw * 4;
    if (rbase >= B * P) return;               // defensive
    const int b = rbase >> 11;
    const float4* vrow = (const float4*)(vg + b * P);
    float acc = 0.0f;
    for (int k = 0; k < 4; ++k) {
        const int r = rbase + k;
        const float ur = u[r];
        const float4* Crow = (const float4*)(C + (size_t)r * P);
        float4* prow = (float4*)(pi + (size_t)r * P);
        for (int it = lane; it < P / 4; it += 64) {
            float4 c4 = Crow[it];
            float4 v4 = vrow[it];
            float4 p4;
            p4.x = __expf((ur + v4.x - c4.x) * INVEPS);
            p4.y = __expf((ur + v4.y - c4.y) * INVEPS);
            p4.z = __expf((ur + v4.z - c4.z) * INVEPS);
            p4.w = __expf((ur + v4.w - c4.w) * INVEPS);
            prow[it] = p4;
            acc += p4.x * c4.x + p4.y * c4.y + p4.z * c4.z + p4.w * c4.w;
        }
    }
#pragma unroll
    for (int off = 32; off; off >>= 1) acc += __shfl_xor(acc, off, 64);
    if (lane == 0) atomicAdd(&sc[b], acc);
    __syncthreads();
    if (tid < B && sc[tid] != 0.0f) atomicAdd(&cost[tid], sc[tid]);
}

extern "C" void kernel_launch(void* const* d_in, const int* in_sizes, int n_in,
                              void* d_out, int out_size, void* d_ws, size_t ws_size,
                              hipStream_t stream) {
    const float* x = (const float*)d_in[0];
    const float* y = (const float*)d_in[1];
    float* out  = (float*)d_out;
    float* cost = out;                              // [8]
    float* pi   = out + 8;                          // [8*2048*2048]
    float* C    = out + 8 + (size_t)B * P * P;      // [8*2048*2048]

    // Column partials live in the pi output region (scratch until final pass).
    float2* part = (float2*)pi;                     // SLABS * B*P float2 = 8 MB

    float* ws      = (float*)d_ws;
    float* u       = ws;                            // B*P
    float* v       = ws + B * P;                    // B*P
    float* errAcc  = ws + 2 * B * P;                // MAXIT
    unsigned* doneArr = (unsigned*)(ws + 2 * B * P + 128);  // MAXIT+1

    hipLaunchKernelGGL(build_C, dim3(8 * 32 * 32), dim3(256), 0, stream, x, y, C);
    hipLaunchKernelGGL(init_ws, dim3(64), dim3(256), 0, stream,
                       u, v, errAcc, doneArr, cost);

    for (int t = 0; t < MAXIT; ++t) {
        hipLaunchKernelGGL(iter_rowcol, dim3(NBLK_A), dim3(256), 0, stream,
                           (const float*)C, (const float*)v, u, part,
                           errAcc, (const unsigned*)doneArr, t);
        hipLaunchKernelGGL(iter_merge, dim3(B * P / 256), dim3(256), 0, stream,
                           (const float2*)part, v, (const float*)errAcc,
                           doneArr, t);
    }

    hipLaunchKernelGGL(final_pi_cost, dim3(1024), dim3(256), 0, stream,
                       (const float*)C, (const float*)u, (const float*)v,
                       pi, cost);
}

// Round 4
// 5717.509 us; speedup vs baseline: 1.4295x; 1.4295x over previous
//
#include <hip/hip_runtime.h>
#include <math.h>

#define B 8
#define P 2048
#define D 64
#define EPS 0.1f
#define INVEPS 10.0f
#define MAXIT 100
#define THRESH 0.1f
#define RSLAB 16
#define SLABS (P / RSLAB)          // 128 slabs per batch
#define NBLK_A (B * SLABS)         // 1024 blocks for iter_rowcol

// ---------------- C build: C[b,i,j] = sum_d (x[b,i,d]-y[b,j,d])^2 ----------
__global__ __launch_bounds__(256) void build_C(const float* __restrict__ x,
                                               const float* __restrict__ y,
                                               float* __restrict__ C) {
    __shared__ float xs[64 * 68];
    __shared__ float ys[64 * 68];
    const int tid = threadIdx.x;
    const int blk = blockIdx.x;        // 8 * 32 * 32 = 8192 blocks
    const int b   = blk >> 10;
    const int rem = blk & 1023;
    const int i0  = (rem >> 5) << 6;
    const int j0  = (rem & 31) << 6;

    const float4* xg = (const float4*)(x + ((size_t)(b * P + i0)) * D);
    const float4* yg = (const float4*)(y + ((size_t)(b * P + j0)) * D);
#pragma unroll
    for (int p = 0; p < 4; ++p) {
        int q = tid + (p << 8);
        int row = q >> 4, c4 = q & 15;
        float4 xv = xg[row * 16 + c4];
        float4 yv = yg[row * 16 + c4];
        float* xd = &xs[row * 68 + (c4 << 2)];
        xd[0] = xv.x; xd[1] = xv.y; xd[2] = xv.z; xd[3] = xv.w;
        float* yd = &ys[row * 68 + (c4 << 2)];
        yd[0] = yv.x; yd[1] = yv.y; yd[2] = yv.z; yd[3] = yv.w;
    }
    __syncthreads();

    const int ti = tid >> 4, tj = tid & 15;
    float acc[4][4] = {};
#pragma unroll 4
    for (int d4 = 0; d4 < 16; ++d4) {
        float4 xa[4], yb[4];
#pragma unroll
        for (int a = 0; a < 4; ++a)
            xa[a] = *(const float4*)&xs[(ti * 4 + a) * 68 + (d4 << 2)];
#pragma unroll
        for (int bb = 0; bb < 4; ++bb)
            yb[bb] = *(const float4*)&ys[(tj * 4 + bb) * 68 + (d4 << 2)];
#pragma unroll
        for (int a = 0; a < 4; ++a)
#pragma unroll
            for (int bb = 0; bb < 4; ++bb) {
                float dx = xa[a].x - yb[bb].x;
                float dy = xa[a].y - yb[bb].y;
                float dz = xa[a].z - yb[bb].z;
                float dw = xa[a].w - yb[bb].w;
                acc[a][bb] += dx * dx + dy * dy + dz * dz + dw * dw;
            }
    }
    size_t base = ((size_t)b * P + (i0 + ti * 4)) * P + (j0 + tj * 4);
#pragma unroll
    for (int a = 0; a < 4; ++a) {
        float4 o = make_float4(acc[a][0], acc[a][1], acc[a][2], acc[a][3]);
        *(float4*)&C[base + (size_t)a * P] = o;
    }
}

// ---------------- online logsumexp helpers --------------------------------
__device__ __forceinline__ void lse_push(float z, float& m, float& s) {
    if (z > m) { s = s * __expf(m - z) + 1.0f; m = z; }
    else       { s += __expf(z - m); }
}
__device__ __forceinline__ void lse_merge(float mo, float so, float& m, float& s) {
    float M = fmaxf(m, mo);
    s = s * __expf(m - M) + so * __expf(mo - M);
    m = M;
}

// ---------------- init: zero u, v, err accumulators, done flags, cost ------
__global__ void init_ws(float* __restrict__ u, float* __restrict__ v,
                        float* __restrict__ errAcc, unsigned* __restrict__ doneArr,
                        float* __restrict__ cost) {
    int idx = blockIdx.x * blockDim.x + threadIdx.x;
    if (idx < B * P) { u[idx] = 0.0f; v[idx] = 0.0f; }
    if (idx < MAXIT) errAcc[idx] = 0.0f;
    if (idx <= MAXIT) doneArr[idx] = 0u;
    if (idx < B) cost[idx] = 0.0f;
}

// ---- iteration kernel A: row-LSE (u update + err) then column partials ----
// block = (batch, slab of 16 rows); 256 threads; 4 row-groups of 4 rows,
// each group staged through LDS so the col pass reads C from LDS not global.
__global__ __launch_bounds__(256, 4) void iter_rowcol(
        const float* __restrict__ C, const float* __restrict__ vg,
        float* __restrict__ u, float2* __restrict__ part,
        float* __restrict__ errAcc, const unsigned* __restrict__ doneArr, int t) {
    if (doneArr[t]) return;
    __shared__ float sC[4 * P];       // 32 KB staged rows for current group
    __shared__ float su[RSLAB];
    __shared__ float serr[4];
    const int tid = threadIdx.x, lane = tid & 63, wid = tid >> 6;
    const int b    = blockIdx.x >> 7;           // / SLABS
    const int slab = blockIdx.x & (SLABS - 1);
    const int r0   = slab * RSLAB;
    const float* Cb = C + (size_t)b * P * P;
    const float4* vrow = (const float4*)(vg + (size_t)b * P);
    const float eps_logmu = EPS * logf(1.0f / (float)P + 1e-8f);

    float cm[8], cs[8];               // col-partial chains (ILP)
#pragma unroll
    for (int k = 0; k < 8; ++k) { cm[k] = -INFINITY; cs[k] = 0.0f; }
    float werr = 0.0f;

    for (int g = 0; g < 4; ++g) {
        // ---- row pass: wave `wid` handles row r0 + 4g + wid ----
        const int r = r0 + g * 4 + wid;
        const float4* Crow = (const float4*)(Cb + (size_t)r * P);
        float4* lrow = (float4*)&sC[wid * P];
        float rm[4] = {-INFINITY, -INFINITY, -INFINITY, -INFINITY};
        float rs[4] = {0.0f, 0.0f, 0.0f, 0.0f};
#pragma unroll
        for (int it0 = 0; it0 < 8; ++it0) {
            int it = lane + (it0 << 6);
            float4 c4 = Crow[it];
            lrow[it] = c4;            // stage for col pass
            float4 v4 = vrow[it];
            lse_push((v4.x - c4.x) * INVEPS, rm[0], rs[0]);
            lse_push((v4.y - c4.y) * INVEPS, rm[1], rs[1]);
            lse_push((v4.z - c4.z) * INVEPS, rm[2], rs[2]);
            lse_push((v4.w - c4.w) * INVEPS, rm[3], rs[3]);
        }
        lse_merge(rm[1], rs[1], rm[0], rs[0]);
        lse_merge(rm[3], rs[3], rm[2], rs[2]);
        lse_merge(rm[2], rs[2], rm[0], rs[0]);
#pragma unroll
        for (int off = 32; off; off >>= 1) {
            float mo = __shfl_xor(rm[0], off, 64);
            float so = __shfl_xor(rs[0], off, 64);
            lse_merge(mo, so, rm[0], rs[0]);
        }
        float unew = eps_logmu - EPS * (rm[0] + logf(rs[0]));
        if (lane == 0) {
            werr += fabsf(unew - u[b * P + r]);
            u[b * P + r] = unew;
            su[g * 4 + wid] = unew;
        }
        __syncthreads();              // publish sC + su for this group

        // ---- col pass over this group's 4 rows, from LDS ----
#pragma unroll
        for (int k = 0; k < 4; ++k) {
            float ur = su[g * 4 + k];
            const float4* lr = (const float4*)&sC[k * P];
            float4 c0 = lr[tid];          // cols 4*tid .. +3
            float4 c1 = lr[tid + 256];    // cols 1024+4*tid .. +3
            lse_push((ur - c0.x) * INVEPS, cm[0], cs[0]);
            lse_push((ur - c0.y) * INVEPS, cm[1], cs[1]);
            lse_push((ur - c0.z) * INVEPS, cm[2], cs[2]);
            lse_push((ur - c0.w) * INVEPS, cm[3], cs[3]);
            lse_push((ur - c1.x) * INVEPS, cm[4], cs[4]);
            lse_push((ur - c1.y) * INVEPS, cm[5], cs[5]);
            lse_push((ur - c1.z) * INVEPS, cm[6], cs[6]);
            lse_push((ur - c1.w) * INVEPS, cm[7], cs[7]);
        }
        __syncthreads();              // protect sC before next group's writes
    }

    if (lane == 0) serr[wid] = werr;
    __syncthreads();
    if (tid == 0) atomicAdd(&errAcc[t], serr[0] + serr[1] + serr[2] + serr[3]);

    // ---- store partials (contiguous float4 pairs) ----
    float2* pbase = part + (size_t)slab * (B * P) + (size_t)b * P;
    *(float4*)&pbase[4 * tid]            = make_float4(cm[0], cs[0], cm[1], cs[1]);
    *(float4*)&pbase[4 * tid + 2]        = make_float4(cm[2], cs[2], cm[3], cs[3]);
    *(float4*)&pbase[1024 + 4 * tid]     = make_float4(cm[4], cs[4], cm[5], cs[5]);
    *(float4*)&pbase[1024 + 4 * tid + 2] = make_float4(cm[6], cs[6], cm[7], cs[7]);
}

// ---- iteration kernel B: merge slab partials -> v; latch done flag --------
__global__ __launch_bounds__(64) void iter_merge(
        const float2* __restrict__ part, float* __restrict__ vg,
        const float* __restrict__ errAcc, unsigned* __restrict__ doneArr, int t) {
    int idx = blockIdx.x * 64 + threadIdx.x;   // 0..B*P-1
    if (idx == 0) {
        // errAcc[t]==0 when frozen, so the latch self-propagates.
        doneArr[t + 1] = doneArr[t] | (errAcc[t] < THRESH * (float)B ? 1u : 0u);
    }
    if (doneArr[t]) return;
    const float eps_logmu = EPS * logf(1.0f / (float)P + 1e-8f);  // log_nu == log_mu
    float m[4], s[4];
#pragma unroll
    for (int c = 0; c < 4; ++c) { m[c] = -INFINITY; s[c] = 0.0f; }
#pragma unroll 4
    for (int k = 0; k < SLABS / 4; ++k) {
#pragma unroll
        for (int c = 0; c < 4; ++c) {
            float2 pk = part[(size_t)(k + (SLABS / 4) * c) * (B * P) + idx];
            lse_merge(pk.x, pk.y, m[c], s[c]);
        }
    }
    lse_merge(m[1], s[1], m[0], s[0]);
    lse_merge(m[3], s[3], m[2], s[2]);
    lse_merge(m[2], s[2], m[0], s[0]);
    vg[idx] = eps_logmu - EPS * (m[0] + logf(s[0]));
}

// ---- final: pi = exp((u+v-C)/eps), cost[b] = sum pi*C ---------------------
// 1024 blocks * 4 waves * 4 rows = 16384 rows = B*P.
__global__ __launch_bounds__(256) void final_pi_cost(
        const float* __restrict__ C, const float* __restrict__ u,
        const float* __restrict__ vg, float* __restrict__ pi,
        float* __restrict__ cost) {
    __shared__ float sc[B];
    const int tid = threadIdx.x, lane = tid & 63, wid = tid >> 6;
    if (tid < B) sc[tid] = 0.0f;
    __syncthreads();
    const int gw = blockIdx.x * 4 + wid;      // 0..4095
    const int rbase = gw * 4;
    if (rbase >= B * P) return;               // defensive
    const int b = rbase >> 11;
    const float4* vrow = (const float4*)(vg + b * P);
    float acc = 0.0f;
    for (int k = 0; k < 4; ++k) {
        const int r = rbase + k;
        const float ur = u[r];
        const float4* Crow = (const float4*)(C + (size_t)r * P);
        float4* prow = (float4*)(pi + (size_t)r * P);
        for (int it = lane; it < P / 4; it += 64) {
            float4 c4 = Crow[it];
            float4 v4 = vrow[it];
            float4 p4;
            p4.x = __expf((ur + v4.x - c4.x) * INVEPS);
            p4.y = __expf((ur + v4.y - c4.y) * INVEPS);
            p4.z = __expf((ur + v4.z - c4.z) * INVEPS);
            p4.w = __expf((ur + v4.w - c4.w) * INVEPS);
            prow[it] = p4;
            acc += p4.x * c4.x + p4.y * c4.y + p4.z * c4.z + p4.w * c4.w;
        }
    }
#pragma unroll
    for (int off = 32; off; off >>= 1) acc += __shfl_xor(acc, off, 64);
    if (lane == 0) atomicAdd(&sc[b], acc);
    __syncthreads();
    if (tid < B && sc[tid] != 0.0f) atomicAdd(&cost[tid], sc[tid]);
}

extern "C" void kernel_launch(void* const* d_in, const int* in_sizes, int n_in,
                              void* d_out, int out_size, void* d_ws, size_t ws_size,
                              hipStream_t stream) {
    const float* x = (const float*)d_in[0];
    const float* y = (const float*)d_in[1];
    float* out  = (float*)d_out;
    float* cost = out;                              // [8]
    float* pi   = out + 8;                          // [8*2048*2048]
    float* C    = out + 8 + (size_t)B * P * P;      // [8*2048*2048]

    // Column partials live in the pi output region (scratch until final pass):
    // SLABS * B*P float2 = 16 MB << 134 MB.
    float2* part = (float2*)pi;

    float* ws      = (float*)d_ws;
    float* u       = ws;                            // B*P
    float* v       = ws + B * P;                    // B*P
    float* errAcc  = ws + 2 * B * P;                // MAXIT
    unsigned* doneArr = (unsigned*)(ws + 2 * B * P + 128);  // MAXIT+1

    hipLaunchKernelGGL(build_C, dim3(8 * 32 * 32), dim3(256), 0, stream, x, y, C);
    hipLaunchKernelGGL(init_ws, dim3(64), dim3(256), 0, stream,
                       u, v, errAcc, doneArr, cost);

    for (int t = 0; t < MAXIT; ++t) {
        hipLaunchKernelGGL(iter_rowcol, dim3(NBLK_A), dim3(256), 0, stream,
                           (const float*)C, (const float*)v, u, part,
                           errAcc, (const unsigned*)doneArr, t);
        hipLaunchKernelGGL(iter_merge, dim3(B * P / 64), dim3(64), 0, stream,
                           (const float2*)part, v, (const float*)errAcc,
                           doneArr, t);
    }

    hipLaunchKernelGGL(final_pi_cost, dim3(1024), dim3(256), 0, stream,
                       (const float*)C, (const float*)u, (const float*)v,
                       pi, cost);
}

// Round 5
// 5300.840 us; speedup vs baseline: 1.5419x; 1.0786x over previous
//
#include <hip/hip_runtime.h>
#include <math.h>

#define B 8
#define P 2048
#define D 64
#define EPS 0.1f
#define INVEPS 10.0f
#define MAXIT 100
#define THRESH 0.1f
#define RSLAB 8                    // rows staged in LDS per slab
#define ROWS_PER_BLK 32            // 4 slabs per block
#define NBLK_A (B * P / ROWS_PER_BLK)   // 512 blocks
#define PLANES (P / ROWS_PER_BLK)       // 64 partial planes per batch

// ---------------- C build: C[b,i,j] = sum_d (x[b,i,d]-y[b,j,d])^2 ----------
__global__ __launch_bounds__(256) void build_C(const float* __restrict__ x,
                                               const float* __restrict__ y,
                                               float* __restrict__ C) {
    __shared__ float xs[64 * 68];
    __shared__ float ys[64 * 68];
    const int tid = threadIdx.x;
    const int blk = blockIdx.x;        // 8 * 32 * 32 = 8192 blocks
    const int b   = blk >> 10;
    const int rem = blk & 1023;
    const int i0  = (rem >> 5) << 6;
    const int j0  = (rem & 31) << 6;

    const float4* xg = (const float4*)(x + ((size_t)(b * P + i0)) * D);
    const float4* yg = (const float4*)(y + ((size_t)(b * P + j0)) * D);
#pragma unroll
    for (int p = 0; p < 4; ++p) {
        int q = tid + (p << 8);
        int row = q >> 4, c4 = q & 15;
        float4 xv = xg[row * 16 + c4];
        float4 yv = yg[row * 16 + c4];
        float* xd = &xs[row * 68 + (c4 << 2)];
        xd[0] = xv.x; xd[1] = xv.y; xd[2] = xv.z; xd[3] = xv.w;
        float* yd = &ys[row * 68 + (c4 << 2)];
        yd[0] = yv.x; yd[1] = yv.y; yd[2] = yv.z; yd[3] = yv.w;
    }
    __syncthreads();

    const int ti = tid >> 4, tj = tid & 15;
    float acc[4][4] = {};
#pragma unroll 4
    for (int d4 = 0; d4 < 16; ++d4) {
        float4 xa[4], yb[4];
#pragma unroll
        for (int a = 0; a < 4; ++a)
            xa[a] = *(const float4*)&xs[(ti * 4 + a) * 68 + (d4 << 2)];
#pragma unroll
        for (int bb = 0; bb < 4; ++bb)
            yb[bb] = *(const float4*)&ys[(tj * 4 + bb) * 68 + (d4 << 2)];
#pragma unroll
        for (int a = 0; a < 4; ++a)
#pragma unroll
            for (int bb = 0; bb < 4; ++bb) {
                float dx = xa[a].x - yb[bb].x;
                float dy = xa[a].y - yb[bb].y;
                float dz = xa[a].z - yb[bb].z;
                float dw = xa[a].w - yb[bb].w;
                acc[a][bb] += dx * dx + dy * dy + dz * dz + dw * dw;
            }
    }
    size_t base = ((size_t)b * P + (i0 + ti * 4)) * P + (j0 + tj * 4);
#pragma unroll
    for (int a = 0; a < 4; ++a) {
        float4 o = make_float4(acc[a][0], acc[a][1], acc[a][2], acc[a][3]);
        *(float4*)&C[base + (size_t)a * P] = o;
    }
}

// ---------------- online logsumexp helpers --------------------------------
__device__ __forceinline__ void lse_push(float z, float& m, float& s) {
    if (z > m) { s = s * __expf(m - z) + 1.0f; m = z; }
    else       { s += __expf(z - m); }
}
__device__ __forceinline__ void lse_merge(float mo, float so, float& m, float& s) {
    float M = fmaxf(m, mo);
    s = s * __expf(m - M) + so * __expf(mo - M);
    m = M;
}

// ---------------- init: zero u, v, err accumulators, done flags, cost ------
__global__ void init_ws(float* __restrict__ u, float* __restrict__ v,
                        float* __restrict__ errAcc, unsigned* __restrict__ doneArr,
                        float* __restrict__ cost) {
    int idx = blockIdx.x * blockDim.x + threadIdx.x;
    if (idx < B * P) { u[idx] = 0.0f; v[idx] = 0.0f; }
    if (idx < MAXIT) errAcc[idx] = 0.0f;
    if (idx <= MAXIT) doneArr[idx] = 0u;
    if (idx < B) cost[idx] = 0.0f;
}

// ---- iteration kernel A: row-LSE (u update + err) then column partials ----
// block = 512 threads = 8 waves; owns 32 rows of one batch, processed as
// 4 slabs of 8 rows staged through 64 KB LDS. v staged in LDS once.
// Col chains accumulate in registers across all 32 rows -> one partial
// plane per block (64 planes per batch).
__global__ __launch_bounds__(512, 4) void iter_rowcol(
        const float* __restrict__ C, const float* __restrict__ vg,
        float* __restrict__ u, float2* __restrict__ part,
        float* __restrict__ errAcc, const unsigned* __restrict__ doneArr, int t) {
    if (doneArr[t]) return;
    __shared__ float sC[RSLAB * P];   // 64 KB: current slab's rows
    __shared__ float sv[P];           // 8 KB: this batch's v
    __shared__ float su[RSLAB];
    __shared__ float serr[8];
    const int tid = threadIdx.x, lane = tid & 63, wid = tid >> 6;  // 8 waves
    const int b  = blockIdx.x >> 6;       // 64 blocks per batch
    const int q  = blockIdx.x & 63;       // row-block within batch
    const int r0 = q * ROWS_PER_BLK;
    const float* Cb = C + (size_t)b * P * P;
    const float eps_logmu = EPS * logf(1.0f / (float)P + 1e-8f);

    // stage v for this batch: 512 threads x 1 float4
    ((float4*)sv)[tid] = ((const float4*)(vg + (size_t)b * P))[tid];

    float cm[4], cs[4];                   // col chains: cols 4*tid..+3
#pragma unroll
    for (int k = 0; k < 4; ++k) { cm[k] = -INFINITY; cs[k] = 0.0f; }
    float werr = 0.0f;
    __syncthreads();                      // sv ready

    for (int sl = 0; sl < 4; ++sl) {
        // ---- row phase: wave `wid` handles row r0 + 8*sl + wid ----
        const int r = r0 + sl * RSLAB + wid;
        const float4* Crow = (const float4*)(Cb + (size_t)r * P);
        float4* lrow = (float4*)&sC[wid * P];
        float rm[4] = {-INFINITY, -INFINITY, -INFINITY, -INFINITY};
        float rs[4] = {0.0f, 0.0f, 0.0f, 0.0f};
#pragma unroll
        for (int k = 0; k < 8; ++k) {
            int it = lane + (k << 6);
            float4 c4 = Crow[it];
            lrow[it] = c4;                // stage for col phase
            float4 v4 = ((const float4*)sv)[it];
            lse_push((v4.x - c4.x) * INVEPS, rm[0], rs[0]);
            lse_push((v4.y - c4.y) * INVEPS, rm[1], rs[1]);
            lse_push((v4.z - c4.z) * INVEPS, rm[2], rs[2]);
            lse_push((v4.w - c4.w) * INVEPS, rm[3], rs[3]);
        }
        lse_merge(rm[1], rs[1], rm[0], rs[0]);
        lse_merge(rm[3], rs[3], rm[2], rs[2]);
        lse_merge(rm[2], rs[2], rm[0], rs[0]);
#pragma unroll
        for (int off = 32; off; off >>= 1) {
            float mo = __shfl_xor(rm[0], off, 64);
            float so = __shfl_xor(rs[0], off, 64);
            lse_merge(mo, so, rm[0], rs[0]);
        }
        float unew = eps_logmu - EPS * (rm[0] + logf(rs[0]));
        if (lane == 0) {
            int gi = b * P + r;
            werr += fabsf(unew - u[gi]);
            u[gi] = unew;
            su[wid] = unew;
        }
        __syncthreads();                  // sC + su ready

        // ---- col phase: 512 threads x 4 cols, 8 rows from LDS ----
#pragma unroll
        for (int rr = 0; rr < RSLAB; ++rr) {
            float ur = su[rr];
            float4 c4 = *(const float4*)&sC[rr * P + (tid << 2)];
            lse_push((ur - c4.x) * INVEPS, cm[0], cs[0]);
            lse_push((ur - c4.y) * INVEPS, cm[1], cs[1]);
            lse_push((ur - c4.z) * INVEPS, cm[2], cs[2]);
            lse_push((ur - c4.w) * INVEPS, cm[3], cs[3]);
        }
        __syncthreads();                  // protect sC/su before next slab
    }

    if (lane == 0) serr[wid] = werr;
    __syncthreads();
    if (tid == 0)
        atomicAdd(&errAcc[t], serr[0] + serr[1] + serr[2] + serr[3] +
                              serr[4] + serr[5] + serr[6] + serr[7]);

    // ---- store partial plane q for batch b (coalesced float4) ----
    float2* pbase = part + ((size_t)q * B + b) * P;
    *(float4*)&pbase[(tid << 2)]     = make_float4(cm[0], cs[0], cm[1], cs[1]);
    *(float4*)&pbase[(tid << 2) + 2] = make_float4(cm[2], cs[2], cm[3], cs[3]);
}

// ---- iteration kernel B: merge 64 planes -> v; latch done flag ------------
__global__ __launch_bounds__(64) void iter_merge(
        const float2* __restrict__ part, float* __restrict__ vg,
        const float* __restrict__ errAcc, unsigned* __restrict__ doneArr, int t) {
    int idx = blockIdx.x * 64 + threadIdx.x;   // 0..B*P-1 (one column each)
    if (idx == 0) {
        // errAcc[t]==0 when frozen, so the latch self-propagates.
        doneArr[t + 1] = doneArr[t] | (errAcc[t] < THRESH * (float)B ? 1u : 0u);
    }
    if (doneArr[t]) return;
    const float eps_logmu = EPS * logf(1.0f / (float)P + 1e-8f);  // log_nu == log_mu
    float m[4], s[4];
#pragma unroll
    for (int c = 0; c < 4; ++c) { m[c] = -INFINITY; s[c] = 0.0f; }
#pragma unroll 4
    for (int k = 0; k < PLANES / 4; ++k) {
#pragma unroll
        for (int c = 0; c < 4; ++c) {
            float2 pk = part[(size_t)(k + (PLANES / 4) * c) * (B * P) + idx];
            lse_merge(pk.x, pk.y, m[c], s[c]);
        }
    }
    lse_merge(m[1], s[1], m[0], s[0]);
    lse_merge(m[3], s[3], m[2], s[2]);
    lse_merge(m[2], s[2], m[0], s[0]);
    vg[idx] = eps_logmu - EPS * (m[0] + logf(s[0]));
}

// ---- final: pi = exp((u+v-C)/eps), cost[b] = sum pi*C ---------------------
// 1024 blocks * 4 waves * 4 rows = 16384 rows = B*P.
__global__ __launch_bounds__(256) void final_pi_cost(
        const float* __restrict__ C, const float* __restrict__ u,
        const float* __restrict__ vg, float* __restrict__ pi,
        float* __restrict__ cost) {
    __shared__ float sc[B];
    const int tid = threadIdx.x, lane = tid & 63, wid = tid >> 6;
    if (tid < B) sc[tid] = 0.0f;
    __syncthreads();
    const int gw = blockIdx.x * 4 + wid;      // 0..4095
    const int rbase = gw * 4;
    if (rbase >= B * P) return;               // defensive
    const int b = rbase >> 11;
    const float4* vrow = (const float4*)(vg + b * P);
    float acc = 0.0f;
    for (int k = 0; k < 4; ++k) {
        const int r = rbase + k;
        const float ur = u[r];
        const float4* Crow = (const float4*)(C + (size_t)r * P);
        float4* prow = (float4*)(pi + (size_t)r * P);
        for (int it = lane; it < P / 4; it += 64) {
            float4 c4 = Crow[it];
            float4 v4 = vrow[it];
            float4 p4;
            p4.x = __expf((ur + v4.x - c4.x) * INVEPS);
            p4.y = __expf((ur + v4.y - c4.y) * INVEPS);
            p4.z = __expf((ur + v4.z - c4.z) * INVEPS);
            p4.w = __expf((ur + v4.w - c4.w) * INVEPS);
            prow[it] = p4;
            acc += p4.x * c4.x + p4.y * c4.y + p4.z * c4.z + p4.w * c4.w;
        }
    }
#pragma unroll
    for (int off = 32; off; off >>= 1) acc += __shfl_xor(acc, off, 64);
    if (lane == 0) atomicAdd(&sc[b], acc);
    __syncthreads();
    if (tid < B && sc[tid] != 0.0f) atomicAdd(&cost[tid], sc[tid]);
}

extern "C" void kernel_launch(void* const* d_in, const int* in_sizes, int n_in,
                              void* d_out, int out_size, void* d_ws, size_t ws_size,
                              hipStream_t stream) {
    const float* x = (const float*)d_in[0];
    const float* y = (const float*)d_in[1];
    float* out  = (float*)d_out;
    float* cost = out;                              // [8]
    float* pi   = out + 8;                          // [8*2048*2048]
    float* C    = out + 8 + (size_t)B * P * P;      // [8*2048*2048]

    // Column partials live in the pi output region (scratch until final pass):
    // PLANES * B*P float2 = 8 MB << 134 MB.
    float2* part = (float2*)pi;

    float* ws      = (float*)d_ws;
    float* u       = ws;                            // B*P
    float* v       = ws + B * P;                    // B*P
    float* errAcc  = ws + 2 * B * P;                // MAXIT
    unsigned* doneArr = (unsigned*)(ws + 2 * B * P + 128);  // MAXIT+1

    hipLaunchKernelGGL(build_C, dim3(8 * 32 * 32), dim3(256), 0, stream, x, y, C);
    hipLaunchKernelGGL(init_ws, dim3(64), dim3(256), 0, stream,
                       u, v, errAcc, doneArr, cost);

    for (int t = 0; t < MAXIT; ++t) {
        hipLaunchKernelGGL(iter_rowcol, dim3(NBLK_A), dim3(512), 0, stream,
                           (const float*)C, (const float*)v, u, part,
                           errAcc, (const unsigned*)doneArr, t);
        hipLaunchKernelGGL(iter_merge, dim3(B * P / 64), dim3(64), 0, stream,
                           (const float2*)part, v, (const float*)errAcc,
                           doneArr, t);
    }

    hipLaunchKernelGGL(final_pi_cost, dim3(1024), dim3(256), 0, stream,
                       (const float*)C, (const float*)u, (const float*)v,
                       pi, cost);
}